// Round 3
// baseline (966.231 us; speedup 1.0000x reference)
//
#include <hip/hip_runtime.h>
#include <hip/hip_bf16.h>

#define D 256        // IN_DIM == HID
#define ED 64        // EDGE_DIM
#define LN_EPS 1e-5f

typedef __attribute__((ext_vector_type(8))) short short8;
typedef __attribute__((ext_vector_type(4))) short short4v;
typedef __attribute__((ext_vector_type(4))) float f32x4;

__device__ __forceinline__ short bf16b(float f) {
    return __builtin_bit_cast(short, __float2bfloat16(f));
}
__device__ __forceinline__ float bf2f(short s) {
    unsigned u = ((unsigned)(unsigned short)s) << 16;
    return __builtin_bit_cast(float, u);
}

__device__ __forceinline__ short8 pack8(float4 f0, float4 f1) {
    short8 r;
    r[0] = bf16b(f0.x); r[1] = bf16b(f0.y); r[2] = bf16b(f0.z); r[3] = bf16b(f0.w);
    r[4] = bf16b(f1.x); r[5] = bf16b(f1.y); r[6] = bf16b(f1.z); r[7] = bf16b(f1.w);
    return r;
}

// ---------------- prep: transpose weights to bf16 ----------------
__global__ __launch_bounds__(256) void prep_weights(
    const float* __restrict__ We, const float* __restrict__ W1,
    const float* __restrict__ W2,
    short* __restrict__ Wet, short* __restrict__ W1t, short* __restrict__ W2t) {
    int t = blockIdx.x * 256 + threadIdx.x;
    if (t < D * ED) {
        int n = t >> 6, k = t & (ED - 1);
        Wet[t] = bf16b(We[k * D + n]);
    }
    if (t < D * D) {
        int n = t >> 8, k = t & (D - 1);
        W1t[t] = bf16b(W1[k * D + n]);
        W2t[t] = bf16b(W2[k * D + n]);
    }
}

// cast x (f32) -> xb (bf16), vectorized
__global__ __launch_bounds__(256) void cast_x(
    const float* __restrict__ x, short* __restrict__ xb, int n4) {
    int t = blockIdx.x * 256 + threadIdx.x;
    if (t < n4) {
        float4 v = ((const float4*)x)[t];
        short4v s;
        s[0] = bf16b(v.x); s[1] = bf16b(v.y); s[2] = bf16b(v.z); s[3] = bf16b(v.w);
        ((short4v*)xb)[t] = s;
    }
}

// ---------------- CSR build ----------------
__global__ __launch_bounds__(256) void hist_kernel(
    const int* __restrict__ dst, int* __restrict__ counts, int E) {
    int t = blockIdx.x * 256 + threadIdx.x;
    if (t < E) atomicAdd(&counts[dst[t]], 1);
}

// exclusive block scan; out = local exclusive prefix, bsum[b] = block total
__global__ __launch_bounds__(256) void scan_block(
    const int* __restrict__ in, int* __restrict__ out, int* __restrict__ bsum, int n) {
    int t = threadIdx.x;
    int g = blockIdx.x * 256 + t;
    int v = (g < n) ? in[g] : 0;
    int lane = t & 63, w = t >> 6;
    int xs = v;
#pragma unroll
    for (int d2 = 1; d2 < 64; d2 <<= 1) {
        int y = __shfl_up(xs, d2, 64);
        if (lane >= d2) xs += y;
    }
    __shared__ int wsums[4];
    if (lane == 63) wsums[w] = xs;
    __syncthreads();
    int addv = 0;
    for (int i = 0; i < w; i++) addv += wsums[i];
    if (g < n) out[g] = xs - v + addv;          // exclusive
    if (t == 255 && bsum != nullptr) bsum[blockIdx.x] = xs + addv;  // total
}

__global__ __launch_bounds__(256) void scan_add(
    int* __restrict__ offs, const int* __restrict__ bofs,
    int* __restrict__ cursor, int n, int Nn) {
    int g = blockIdx.x * 256 + threadIdx.x;
    if (g < n) {
        int v = offs[g] + bofs[blockIdx.x];
        offs[g] = v;
        if (g < Nn) cursor[g] = v;
    }
}

__global__ __launch_bounds__(256) void scatter_edges(
    const int* __restrict__ src, const int* __restrict__ dst,
    int* __restrict__ cursor, int* __restrict__ perm,
    int* __restrict__ srcP, int* __restrict__ dstP, int E) {
    int t = blockIdx.x * 256 + threadIdx.x;
    if (t < E) {
        int d = dst[t];
        int p = atomicAdd(&cursor[d], 1);
        perm[p] = t;
        srcP[p] = src[t];
        dstP[p] = d;
    }
}

// ---------------- fused edge GEMM + segmented aggregation ----------------
// Block = 64 permuted (dst-sorted) edges, 4 waves. Computes
// m = relu(ea[perm]@We + be + xb[src]) into LDS, then segment-sums rows
// by dst and flushes to aggr (plain store for fully-contained segments,
// atomic for block-boundary segments).
__global__ __launch_bounds__(256) void fused_edge(
    const float* __restrict__ ea, const int* __restrict__ perm,
    const int* __restrict__ srcP, const int* __restrict__ dstP,
    const int* __restrict__ offs, const short* __restrict__ Wet,
    const float* __restrict__ be, const short* __restrict__ xb,
    float* __restrict__ aggr, int E) {
    __shared__ short tile[64][D + 8];
    __shared__ int sdst[64];
    const int t    = threadIdx.x;
    const int lane = t & 63;
    const int w    = t >> 6;
    const int q    = lane >> 4;
    const int ln   = lane & 15;
    const int blockBase = blockIdx.x * 64;
    const long eBase = (long)blockBase + w * 16;

    if (t < 64) {
        int p = blockBase + t;
        sdst[t] = (p < E) ? dstP[p] : -1;
    }

    // ---- A fragments: permuted edge rows, f32 -> bf16 ----
    long em = eBase + ln;
    if (em >= E) em = E - 1;
    int eid = perm[em];
    const float* ear = ea + (long)eid * ED + q * 8;
    float4 f0 = *(const float4*)(ear);
    float4 f1 = *(const float4*)(ear + 4);
    float4 f2 = *(const float4*)(ear + 32);
    float4 f3 = *(const float4*)(ear + 36);
    short8 a0 = pack8(f0, f1);
    short8 a1 = pack8(f2, f3);

    // src ids for epilogue gather
    int srcs[4]; bool valid[4];
#pragma unroll
    for (int r = 0; r < 4; r++) {
        long e = eBase + q * 4 + r;
        valid[r] = (e < E);
        srcs[r] = srcP[valid[r] ? e : 0];
    }

    // ---- MFMA + epilogue: relu(msg + be + x[src]) -> bf16 tile ----
#pragma unroll
    for (int nt = 0; nt < 16; nt++) {
        const short* wp = Wet + (nt * 16 + ln) * ED + q * 8;
        short8 b0 = *(const short8*)(wp);
        short8 b1 = *(const short8*)(wp + 32);
        f32x4 c = {0.f, 0.f, 0.f, 0.f};
        c = __builtin_amdgcn_mfma_f32_16x16x32_bf16(a0, b0, c, 0, 0, 0);
        c = __builtin_amdgcn_mfma_f32_16x16x32_bf16(a1, b1, c, 0, 0, 0);
        int col = nt * 16 + ln;
        float bev = be[col];
#pragma unroll
        for (int r = 0; r < 4; r++) {
            float v = 0.f;
            if (valid[r]) {
                float xv = bf2f(xb[(long)srcs[r] * D + col]);
                v = fmaxf(c[r] + bev + xv, 0.f);
            }
            tile[w * 16 + q * 4 + r][col] = bf16b(v);
        }
    }
    __syncthreads();

    // ---- segmented column-pass: thread t owns column t ----
    const int c = t;
    float s = 0.f;
    int cur = sdst[0];
#pragma unroll
    for (int row = 0; row < 64; row++) {
        int d = sdst[row];
        if (d != cur) {
            if (cur >= 0) {   // flush (block-uniform branch)
                int gs = offs[cur], ge = offs[cur + 1];
                float* ap = &aggr[(long)cur * D + c];
                if (gs >= blockBase && ge <= blockBase + 64) *ap = s;
                else unsafeAtomicAdd(ap, s);
            }
            cur = d;
            s = 0.f;
        }
        s += bf2f(tile[row][c]);
    }
    if (cur >= 0) {
        int gs = offs[cur], ge = offs[cur + 1];
        float* ap = &aggr[(long)cur * D + c];
        if (gs >= blockBase && ge <= blockBase + 64) *ap = s;
        else unsafeAtomicAdd(ap, s);
    }
}

// ---------------- fused MLP + LN (z = x + aggr) ----------------
__global__ __launch_bounds__(256) void mlp_kernel(
    const float* __restrict__ x, const float* __restrict__ aggr,
    const short* __restrict__ W1t, const float* __restrict__ b1,
    const short* __restrict__ W2t, const float* __restrict__ b2,
    const float* __restrict__ gamma, const float* __restrict__ beta,
    float* __restrict__ out, int N) {
    __shared__ short tile[64][D + 8];
    const int t = threadIdx.x;
    const int rowBase = blockIdx.x * 64;

    // phase 1: z = x + aggr -> bf16 LDS tile
    {
        int c4 = t & 63;
        int r0 = t >> 6;
#pragma unroll
        for (int i = 0; i < 16; i++) {
            int row = i * 4 + r0;
            int grow = rowBase + row;
            int gr = grow < N ? grow : N - 1;
            float4 xv = *((const float4*)(x + (long)gr * D) + c4);
            float4 av = *((const float4*)(aggr + (long)gr * D) + c4);
            short4v sv;
            sv[0] = bf16b(xv.x + av.x);
            sv[1] = bf16b(xv.y + av.y);
            sv[2] = bf16b(xv.z + av.z);
            sv[3] = bf16b(xv.w + av.w);
            *(short4v*)&tile[row][c4 * 4] = sv;
        }
    }
    __syncthreads();

    const int lane = t & 63;
    const int w    = t >> 6;
    const int q    = lane >> 4;
    const int ln   = lane & 15;
    const int mrow = w * 16;

    // phase 2: GEMM1
    f32x4 acc[16];
#pragma unroll
    for (int nt = 0; nt < 16; nt++) acc[nt] = (f32x4){0.f, 0.f, 0.f, 0.f};
#pragma unroll
    for (int s = 0; s < 8; s++) {
        int k = s * 32 + q * 8;
        short8 a = *(const short8*)&tile[mrow + ln][k];
#pragma unroll
        for (int nt = 0; nt < 16; nt++) {
            short8 b = *(const short8*)(W1t + (nt * 16 + ln) * D + k);
            acc[nt] = __builtin_amdgcn_mfma_f32_16x16x32_bf16(a, b, acc[nt], 0, 0, 0);
        }
    }

    // phase 3: h1 = relu(acc + b1) -> own rows of tile (wave-private, no barrier)
#pragma unroll
    for (int nt = 0; nt < 16; nt++) {
        int col = nt * 16 + ln;
        float bv = b1[col];
#pragma unroll
        for (int r = 0; r < 4; r++) {
            float v = fmaxf(acc[nt][r] + bv, 0.f);
            tile[mrow + q * 4 + r][col] = bf16b(v);
        }
    }

    // phase 4: GEMM2
    f32x4 acc2[16];
#pragma unroll
    for (int nt = 0; nt < 16; nt++) acc2[nt] = (f32x4){0.f, 0.f, 0.f, 0.f};
#pragma unroll
    for (int s = 0; s < 8; s++) {
        int k = s * 32 + q * 8;
        short8 a = *(const short8*)&tile[mrow + ln][k];
#pragma unroll
        for (int nt = 0; nt < 16; nt++) {
            short8 b = *(const short8*)(W2t + (nt * 16 + ln) * D + k);
            acc2[nt] = __builtin_amdgcn_mfma_f32_16x16x32_bf16(a, b, acc2[nt], 0, 0, 0);
        }
    }

    // phase 5: relu + residual + LayerNorm
    float sum[4] = {0.f, 0.f, 0.f, 0.f};
    float sumsq[4] = {0.f, 0.f, 0.f, 0.f};
#pragma unroll
    for (int nt = 0; nt < 16; nt++) {
        int col = nt * 16 + ln;
        float b2v = b2[col];
#pragma unroll
        for (int r = 0; r < 4; r++) {
            int row = rowBase + mrow + q * 4 + r;
            int rc = row < N ? row : N - 1;
            float v = fmaxf(acc2[nt][r] + b2v, 0.f) + x[(long)rc * D + col];
            acc2[nt][r] = v;
            sum[r] += v;
            sumsq[r] += v * v;
        }
    }
#pragma unroll
    for (int m = 1; m <= 8; m <<= 1) {
#pragma unroll
        for (int r = 0; r < 4; r++) {
            sum[r]   += __shfl_xor(sum[r], m, 64);
            sumsq[r] += __shfl_xor(sumsq[r], m, 64);
        }
    }
    float mean[4], rstd[4];
#pragma unroll
    for (int r = 0; r < 4; r++) {
        mean[r] = sum[r] * (1.f / 256.f);
        float var = sumsq[r] * (1.f / 256.f) - mean[r] * mean[r];
        rstd[r] = rsqrtf(var + LN_EPS);
    }
#pragma unroll
    for (int nt = 0; nt < 16; nt++) {
        int col = nt * 16 + ln;
        float g = gamma[col], bb = beta[col];
#pragma unroll
        for (int r = 0; r < 4; r++) {
            int row = rowBase + mrow + q * 4 + r;
            if (row < N) {
                out[(long)row * D + col] = (acc2[nt][r] - mean[r]) * rstd[r] * g + bb;
            }
        }
    }
}

// ================= fallback path (round-1, atomics) =================
__global__ __launch_bounds__(256) void edge_kernel_v1(
    const float* __restrict__ ea, const int* __restrict__ src,
    const int* __restrict__ dst, const short* __restrict__ Wet,
    const float* __restrict__ be, const float* __restrict__ x,
    float* __restrict__ aggr, int E) {
    const int lane = threadIdx.x & 63;
    const int w    = threadIdx.x >> 6;
    const int q    = lane >> 4;
    const int ln   = lane & 15;
    const long eBase = (long)blockIdx.x * 64 + w * 16;
    long em = eBase + ln;
    if (em >= E) em = E - 1;
    const float* ear = ea + em * ED + q * 8;
    float4 f0 = *(const float4*)(ear);
    float4 f1 = *(const float4*)(ear + 4);
    float4 f2 = *(const float4*)(ear + 32);
    float4 f3 = *(const float4*)(ear + 36);
    short8 a0 = pack8(f0, f1);
    short8 a1 = pack8(f2, f3);
    f32x4 acc[16];
#pragma unroll
    for (int nt = 0; nt < 16; nt++) {
        const short* wp = Wet + (nt * 16 + ln) * ED + q * 8;
        short8 b0 = *(const short8*)(wp);
        short8 b1 = *(const short8*)(wp + 32);
        f32x4 c = {0.f, 0.f, 0.f, 0.f};
        c = __builtin_amdgcn_mfma_f32_16x16x32_bf16(a0, b0, c, 0, 0, 0);
        c = __builtin_amdgcn_mfma_f32_16x16x32_bf16(a1, b1, c, 0, 0, 0);
        acc[nt] = c;
    }
    int srcs[4], dsts[4];
    bool valid[4];
#pragma unroll
    for (int r = 0; r < 4; r++) {
        long e = eBase + q * 4 + r;
        valid[r] = (e < E);
        long ec = valid[r] ? e : 0;
        srcs[r] = src[ec];
        dsts[r] = dst[ec];
    }
#pragma unroll
    for (int nt = 0; nt < 16; nt++) {
        int col = nt * 16 + ln;
        float bev = be[col];
#pragma unroll
        for (int r = 0; r < 4; r++) {
            if (valid[r]) {
                float v = acc[nt][r] + bev + x[(long)srcs[r] * D + col];
                v = fmaxf(v, 0.f);
                unsafeAtomicAdd(&aggr[(long)dsts[r] * D + col], v);
            }
        }
    }
}

// ================= host =================
extern "C" void kernel_launch(void* const* d_in, const int* in_sizes, int n_in,
                              void* d_out, int out_size, void* d_ws, size_t ws_size,
                              hipStream_t stream) {
    const float* x     = (const float*)d_in[0];
    const int*   ei    = (const int*)d_in[1];
    const float* ea    = (const float*)d_in[2];
    const float* We    = (const float*)d_in[3];
    const float* be    = (const float*)d_in[4];
    const float* W1    = (const float*)d_in[5];
    const float* b1    = (const float*)d_in[6];
    const float* W2    = (const float*)d_in[7];
    const float* b2    = (const float*)d_in[8];
    const float* gamma = (const float*)d_in[9];
    const float* beta  = (const float*)d_in[10];

    const int N = in_sizes[0] / D;
    const int E = in_sizes[1] / 2;
    const int* src = ei;
    const int* dst = ei + E;

    // ---- workspace layout (256B-aligned slabs) ----
    char* ws = (char*)d_ws;
    size_t off = 0;
    auto alloc = [&](size_t bytes) -> size_t {
        size_t o = off;
        off = (off + bytes + 255) & ~(size_t)255;
        return o;
    };
    size_t o_offs   = alloc((size_t)(N + 1) * 4);
    size_t o_counts = alloc((size_t)(N + 1) * 4);
    size_t o_cursor = alloc((size_t)N * 4);
    size_t o_bsum   = alloc(256 * 4);
    size_t o_bofs   = alloc(256 * 4);
    size_t o_perm   = alloc((size_t)E * 4);
    size_t o_srcP   = alloc((size_t)E * 4);
    size_t o_dstP   = alloc((size_t)E * 4);
    size_t o_Wet    = alloc((size_t)D * ED * 2);
    size_t o_W1t    = alloc((size_t)D * D * 2);
    size_t o_W2t    = alloc((size_t)D * D * 2);
    size_t o_xb     = alloc((size_t)N * D * 2);
    size_t o_aggr   = alloc((size_t)N * D * 4);
    size_t need = off;

    if (ws_size >= need) {
        // ---------- CSR + fused two-phase path ----------
        int*   offs   = (int*)(ws + o_offs);
        int*   counts = (int*)(ws + o_counts);
        int*   cursor = (int*)(ws + o_cursor);
        int*   bsum   = (int*)(ws + o_bsum);
        int*   bofs   = (int*)(ws + o_bofs);
        int*   perm   = (int*)(ws + o_perm);
        int*   srcP   = (int*)(ws + o_srcP);
        int*   dstP   = (int*)(ws + o_dstP);
        short* Wet    = (short*)(ws + o_Wet);
        short* W1t    = (short*)(ws + o_W1t);
        short* W2t    = (short*)(ws + o_W2t);
        short* xb     = (short*)(ws + o_xb);
        float* aggr   = (float*)(ws + o_aggr);

        hipMemsetAsync(counts, 0, (size_t)(N + 1) * 4, stream);
        hipMemsetAsync(aggr, 0, (size_t)N * D * 4, stream);
        prep_weights<<<dim3(256), dim3(256), 0, stream>>>(We, W1, W2, Wet, W1t, W2t);
        int n4 = N * D / 4;
        cast_x<<<dim3((n4 + 255) / 256), dim3(256), 0, stream>>>(x, xb, n4);

        hist_kernel<<<dim3((E + 255) / 256), dim3(256), 0, stream>>>(dst, counts, E);
        int nscan = N + 1;
        int nb = (nscan + 255) / 256;
        scan_block<<<dim3(nb), dim3(256), 0, stream>>>(counts, offs, bsum, nscan);
        scan_block<<<dim3(1), dim3(256), 0, stream>>>(bsum, bofs, (int*)nullptr, nb);
        scan_add<<<dim3(nb), dim3(256), 0, stream>>>(offs, bofs, cursor, nscan, N);
        scatter_edges<<<dim3((E + 255) / 256), dim3(256), 0, stream>>>(
            src, dst, cursor, perm, srcP, dstP, E);

        fused_edge<<<dim3((E + 63) / 64), dim3(256), 0, stream>>>(
            ea, perm, srcP, dstP, offs, Wet, be, xb, aggr, E);
        mlp_kernel<<<dim3((N + 63) / 64), dim3(256), 0, stream>>>(
            x, aggr, W1t, b1, W2t, b2, gamma, beta, (float*)d_out, N);
    } else {
        // ---------- fallback: round-1 atomic path ----------
        float* aggr = (float*)ws;
        size_t aggrB = (size_t)N * D * sizeof(float);
        short* Wet = (short*)(ws + aggrB);
        short* W1t = Wet + D * ED;
        short* W2t = W1t + D * D;

        hipMemsetAsync(aggr, 0, aggrB, stream);
        prep_weights<<<dim3(256), dim3(256), 0, stream>>>(We, W1, W2, Wet, W1t, W2t);
        edge_kernel_v1<<<dim3((E + 63) / 64), dim3(256), 0, stream>>>(ea, src, dst, Wet, be, x, aggr, E);
        mlp_kernel<<<dim3((N + 63) / 64), dim3(256), 0, stream>>>(
            x, aggr, W1t, b1, W2t, b2, gamma, beta, (float*)d_out, N);
    }
}

// Round 4
// 802.993 us; speedup vs baseline: 1.2033x; 1.2033x over previous
//
#include <hip/hip_runtime.h>
#include <hip/hip_bf16.h>

#define D 256        // IN_DIM == HID
#define ED 64        // EDGE_DIM
#define LN_EPS 1e-5f

typedef __attribute__((ext_vector_type(8))) short short8;
typedef __attribute__((ext_vector_type(4))) short short4v;
typedef __attribute__((ext_vector_type(4))) float f32x4;

__device__ __forceinline__ short bf16b(float f) {
    return __builtin_bit_cast(short, __float2bfloat16(f));
}
__device__ __forceinline__ float bf2f(short s) {
    unsigned u = ((unsigned)(unsigned short)s) << 16;
    return __builtin_bit_cast(float, u);
}

__device__ __forceinline__ short8 pack8(float4 f0, float4 f1) {
    short8 r;
    r[0] = bf16b(f0.x); r[1] = bf16b(f0.y); r[2] = bf16b(f0.z); r[3] = bf16b(f0.w);
    r[4] = bf16b(f1.x); r[5] = bf16b(f1.y); r[6] = bf16b(f1.z); r[7] = bf16b(f1.w);
    return r;
}

// ---------------- prep: transpose weights to bf16 ----------------
__global__ __launch_bounds__(256) void prep_weights(
    const float* __restrict__ We, const float* __restrict__ W1,
    const float* __restrict__ W2,
    short* __restrict__ Wet, short* __restrict__ W1t, short* __restrict__ W2t) {
    int t = blockIdx.x * 256 + threadIdx.x;
    if (t < D * ED) {
        int n = t >> 6, k = t & (ED - 1);
        Wet[t] = bf16b(We[k * D + n]);
    }
    if (t < D * D) {
        int n = t >> 8, k = t & (D - 1);
        W1t[t] = bf16b(W1[k * D + n]);
        W2t[t] = bf16b(W2[k * D + n]);
    }
}

// cast x (f32) -> xb (bf16), vectorized
__global__ __launch_bounds__(256) void cast_x(
    const float* __restrict__ x, short* __restrict__ xb, int n4) {
    int t = blockIdx.x * 256 + threadIdx.x;
    if (t < n4) {
        float4 v = ((const float4*)x)[t];
        short4v s;
        s[0] = bf16b(v.x); s[1] = bf16b(v.y); s[2] = bf16b(v.z); s[3] = bf16b(v.w);
        ((short4v*)xb)[t] = s;
    }
}

// ---------------- CSR build ----------------
__global__ __launch_bounds__(256) void hist_kernel(
    const int* __restrict__ dst, int* __restrict__ counts, int E) {
    int t = blockIdx.x * 256 + threadIdx.x;
    if (t < E) atomicAdd(&counts[dst[t]], 1);
}

__global__ __launch_bounds__(256) void scan_block(
    const int* __restrict__ in, int* __restrict__ out, int* __restrict__ bsum, int n) {
    int t = threadIdx.x;
    int g = blockIdx.x * 256 + t;
    int v = (g < n) ? in[g] : 0;
    int lane = t & 63, w = t >> 6;
    int xs = v;
#pragma unroll
    for (int d2 = 1; d2 < 64; d2 <<= 1) {
        int y = __shfl_up(xs, d2, 64);
        if (lane >= d2) xs += y;
    }
    __shared__ int wsums[4];
    if (lane == 63) wsums[w] = xs;
    __syncthreads();
    int addv = 0;
    for (int i = 0; i < w; i++) addv += wsums[i];
    if (g < n) out[g] = xs - v + addv;          // exclusive
    if (t == 255 && bsum != nullptr) bsum[blockIdx.x] = xs + addv;  // total
}

__global__ __launch_bounds__(256) void scan_add(
    int* __restrict__ offs, const int* __restrict__ bofs,
    int* __restrict__ cursor, int n, int Nn) {
    int g = blockIdx.x * 256 + threadIdx.x;
    if (g < n) {
        int v = offs[g] + bofs[blockIdx.x];
        offs[g] = v;
        if (g < Nn) cursor[g] = v;
    }
}

__global__ __launch_bounds__(256) void scatter_edges(
    const int* __restrict__ src, const int* __restrict__ dst,
    int* __restrict__ cursor, int* __restrict__ perm,
    int* __restrict__ srcP, int* __restrict__ dstP, int E) {
    int t = blockIdx.x * 256 + threadIdx.x;
    if (t < E) {
        int d = dst[t];
        int p = atomicAdd(&cursor[d], 1);
        perm[p] = t;
        srcP[p] = src[t];
        dstP[p] = d;
    }
}

// ---------------- fused edge GEMM + segmented aggregation (v2) ----------------
// Block = 64 dst-sorted edges, 4 waves.
// A: stage ea rows (LDS, bf16) + xb[src] rows (registers, short8 x8)
// B: MFMA msg = ea@We + be -> bf16 LDS tile (C-layout write, conflict-free)
// C: row-major in-place fixup: tile = bf16(relu(msg + x_src))
// D: segmented column sum by dst; contained segs -> store, boundary -> atomic
__global__ __launch_bounds__(256) void fused_edge(
    const float* __restrict__ ea, const int* __restrict__ perm,
    const int* __restrict__ srcP, const int* __restrict__ dstP,
    const int* __restrict__ offs, const short* __restrict__ Wet,
    const float* __restrict__ be, const short* __restrict__ xb,
    float* __restrict__ aggr, int E) {
    __shared__ short atile[64][ED + 8];   // 9.2 KB  (stride 144 B: 16B-aligned, conflict-free frags)
    __shared__ short tile[64][D + 8];     // 33.8 KB
    __shared__ int sdst[64];
    const int t = threadIdx.x;
    const int blockBase = blockIdx.x * 64;

    // ---- Phase A: wide staging ----
    const int rt  = t >> 2;     // edge row 0..63
    const int seg = t & 3;      // row quarter
    int p = blockBase + rt;
    const bool rowValid = (p < E);
    int pc = rowValid ? p : E - 1;
    int eid = perm[pc];
    int sid = srcP[pc];
    if (seg == 0) sdst[rt] = rowValid ? dstP[pc] : -1;

    const float4* ep = (const float4*)(ea + (long)eid * ED + seg * 16);
    float4 e0 = ep[0], e1 = ep[1], e2 = ep[2], e3 = ep[3];

    const short8* xp = (const short8*)(xb + (long)sid * D + seg * 64);
    short8 xr[8];
#pragma unroll
    for (int i = 0; i < 8; i++) xr[i] = xp[i];

    *(short8*)&atile[rt][seg * 16]     = pack8(e0, e1);
    *(short8*)&atile[rt][seg * 16 + 8] = pack8(e2, e3);
    __syncthreads();

    // ---- Phase B: MFMA ----
    const int lane = t & 63;
    const int w    = t >> 6;
    const int q    = lane >> 4;
    const int ln   = lane & 15;
    short8 a0 = *(const short8*)&atile[w * 16 + ln][q * 8];
    short8 a1 = *(const short8*)&atile[w * 16 + ln][32 + q * 8];
#pragma unroll
    for (int nt = 0; nt < 16; nt++) {
        const short* wp = Wet + (nt * 16 + ln) * ED + q * 8;
        short8 b0 = *(const short8*)(wp);
        short8 b1 = *(const short8*)(wp + 32);
        f32x4 c = {0.f, 0.f, 0.f, 0.f};
        c = __builtin_amdgcn_mfma_f32_16x16x32_bf16(a0, b0, c, 0, 0, 0);
        c = __builtin_amdgcn_mfma_f32_16x16x32_bf16(a1, b1, c, 0, 0, 0);
        int col = nt * 16 + ln;
        float bev = be[col];
#pragma unroll
        for (int r = 0; r < 4; r++)
            tile[w * 16 + q * 4 + r][col] = bf16b(c[r] + bev);
    }
    __syncthreads();

    // ---- Phase C: row-major fixup with registered x rows ----
    {
        short* row = &tile[rt][seg * 64];
#pragma unroll
        for (int i = 0; i < 8; i++) {
            short8 m = *(short8*)(row + i * 8);
            short8 o;
#pragma unroll
            for (int k2 = 0; k2 < 8; k2++) {
                float v = rowValid ? fmaxf(bf2f(m[k2]) + bf2f(xr[i][k2]), 0.f) : 0.f;
                o[k2] = bf16b(v);
            }
            *(short8*)(row + i * 8) = o;
        }
    }
    __syncthreads();

    // ---- Phase D: segmented column-pass ----
    const int c = t;
    float s = 0.f;
    int cur = sdst[0];
#pragma unroll
    for (int row = 0; row < 64; row++) {
        int d = sdst[row];
        if (d != cur) {
            if (cur >= 0) {
                int gs = offs[cur], ge = offs[cur + 1];
                float* ap = &aggr[(long)cur * D + c];
                if (gs >= blockBase && ge <= blockBase + 64) *ap = s;
                else unsafeAtomicAdd(ap, s);
            }
            cur = d;
            s = 0.f;
        }
        s += bf2f(tile[row][c]);
    }
    if (cur >= 0) {
        int gs = offs[cur], ge = offs[cur + 1];
        float* ap = &aggr[(long)cur * D + c];
        if (gs >= blockBase && ge <= blockBase + 64) *ap = s;
        else unsafeAtomicAdd(ap, s);
    }
}

// ---------------- fused MLP + LN (z = x + aggr) ----------------
__global__ __launch_bounds__(256) void mlp_kernel(
    const float* __restrict__ x, const float* __restrict__ aggr,
    const short* __restrict__ W1t, const float* __restrict__ b1,
    const short* __restrict__ W2t, const float* __restrict__ b2,
    const float* __restrict__ gamma, const float* __restrict__ beta,
    float* __restrict__ out, int N) {
    __shared__ short tile[64][D + 8];
    const int t = threadIdx.x;
    const int rowBase = blockIdx.x * 64;

    {
        int c4 = t & 63;
        int r0 = t >> 6;
#pragma unroll
        for (int i = 0; i < 16; i++) {
            int row = i * 4 + r0;
            int grow = rowBase + row;
            int gr = grow < N ? grow : N - 1;
            float4 xv = *((const float4*)(x + (long)gr * D) + c4);
            float4 av = *((const float4*)(aggr + (long)gr * D) + c4);
            short4v sv;
            sv[0] = bf16b(xv.x + av.x);
            sv[1] = bf16b(xv.y + av.y);
            sv[2] = bf16b(xv.z + av.z);
            sv[3] = bf16b(xv.w + av.w);
            *(short4v*)&tile[row][c4 * 4] = sv;
        }
    }
    __syncthreads();

    const int lane = t & 63;
    const int w    = t >> 6;
    const int q    = lane >> 4;
    const int ln   = lane & 15;
    const int mrow = w * 16;

    f32x4 acc[16];
#pragma unroll
    for (int nt = 0; nt < 16; nt++) acc[nt] = (f32x4){0.f, 0.f, 0.f, 0.f};
#pragma unroll
    for (int s = 0; s < 8; s++) {
        int k = s * 32 + q * 8;
        short8 a = *(const short8*)&tile[mrow + ln][k];
#pragma unroll
        for (int nt = 0; nt < 16; nt++) {
            short8 b = *(const short8*)(W1t + (nt * 16 + ln) * D + k);
            acc[nt] = __builtin_amdgcn_mfma_f32_16x16x32_bf16(a, b, acc[nt], 0, 0, 0);
        }
    }

#pragma unroll
    for (int nt = 0; nt < 16; nt++) {
        int col = nt * 16 + ln;
        float bv = b1[col];
#pragma unroll
        for (int r = 0; r < 4; r++) {
            float v = fmaxf(acc[nt][r] + bv, 0.f);
            tile[mrow + q * 4 + r][col] = bf16b(v);
        }
    }

    f32x4 acc2[16];
#pragma unroll
    for (int nt = 0; nt < 16; nt++) acc2[nt] = (f32x4){0.f, 0.f, 0.f, 0.f};
#pragma unroll
    for (int s = 0; s < 8; s++) {
        int k = s * 32 + q * 8;
        short8 a = *(const short8*)&tile[mrow + ln][k];
#pragma unroll
        for (int nt = 0; nt < 16; nt++) {
            short8 b = *(const short8*)(W2t + (nt * 16 + ln) * D + k);
            acc2[nt] = __builtin_amdgcn_mfma_f32_16x16x32_bf16(a, b, acc2[nt], 0, 0, 0);
        }
    }

    float sum[4] = {0.f, 0.f, 0.f, 0.f};
    float sumsq[4] = {0.f, 0.f, 0.f, 0.f};
#pragma unroll
    for (int nt = 0; nt < 16; nt++) {
        int col = nt * 16 + ln;
        float b2v = b2[col];
#pragma unroll
        for (int r = 0; r < 4; r++) {
            int row = rowBase + mrow + q * 4 + r;
            int rc = row < N ? row : N - 1;
            float v = fmaxf(acc2[nt][r] + b2v, 0.f) + x[(long)rc * D + col];
            acc2[nt][r] = v;
            sum[r] += v;
            sumsq[r] += v * v;
        }
    }
#pragma unroll
    for (int m = 1; m <= 8; m <<= 1) {
#pragma unroll
        for (int r = 0; r < 4; r++) {
            sum[r]   += __shfl_xor(sum[r], m, 64);
            sumsq[r] += __shfl_xor(sumsq[r], m, 64);
        }
    }
    float mean[4], rstd[4];
#pragma unroll
    for (int r = 0; r < 4; r++) {
        mean[r] = sum[r] * (1.f / 256.f);
        float var = sumsq[r] * (1.f / 256.f) - mean[r] * mean[r];
        rstd[r] = rsqrtf(var + LN_EPS);
    }
#pragma unroll
    for (int nt = 0; nt < 16; nt++) {
        int col = nt * 16 + ln;
        float g = gamma[col], bb = beta[col];
#pragma unroll
        for (int r = 0; r < 4; r++) {
            int row = rowBase + mrow + q * 4 + r;
            if (row < N) {
                out[(long)row * D + col] = (acc2[nt][r] - mean[r]) * rstd[r] * g + bb;
            }
        }
    }
}

// ================= fallback path (round-1, atomics) =================
__global__ __launch_bounds__(256) void edge_kernel_v1(
    const float* __restrict__ ea, const int* __restrict__ src,
    const int* __restrict__ dst, const short* __restrict__ Wet,
    const float* __restrict__ be, const float* __restrict__ x,
    float* __restrict__ aggr, int E) {
    const int lane = threadIdx.x & 63;
    const int w    = threadIdx.x >> 6;
    const int q    = lane >> 4;
    const int ln   = lane & 15;
    const long eBase = (long)blockIdx.x * 64 + w * 16;
    long em = eBase + ln;
    if (em >= E) em = E - 1;
    const float* ear = ea + em * ED + q * 8;
    float4 f0 = *(const float4*)(ear);
    float4 f1 = *(const float4*)(ear + 4);
    float4 f2 = *(const float4*)(ear + 32);
    float4 f3 = *(const float4*)(ear + 36);
    short8 a0 = pack8(f0, f1);
    short8 a1 = pack8(f2, f3);
    f32x4 acc[16];
#pragma unroll
    for (int nt = 0; nt < 16; nt++) {
        const short* wp = Wet + (nt * 16 + ln) * ED + q * 8;
        short8 b0 = *(const short8*)(wp);
        short8 b1 = *(const short8*)(wp + 32);
        f32x4 c = {0.f, 0.f, 0.f, 0.f};
        c = __builtin_amdgcn_mfma_f32_16x16x32_bf16(a0, b0, c, 0, 0, 0);
        c = __builtin_amdgcn_mfma_f32_16x16x32_bf16(a1, b1, c, 0, 0, 0);
        acc[nt] = c;
    }
    int srcs[4], dsts[4];
    bool valid[4];
#pragma unroll
    for (int r = 0; r < 4; r++) {
        long e = eBase + q * 4 + r;
        valid[r] = (e < E);
        long ec = valid[r] ? e : 0;
        srcs[r] = src[ec];
        dsts[r] = dst[ec];
    }
#pragma unroll
    for (int nt = 0; nt < 16; nt++) {
        int col = nt * 16 + ln;
        float bev = be[col];
#pragma unroll
        for (int r = 0; r < 4; r++) {
            if (valid[r]) {
                float v = acc[nt][r] + bev + x[(long)srcs[r] * D + col];
                v = fmaxf(v, 0.f);
                unsafeAtomicAdd(&aggr[(long)dsts[r] * D + col], v);
            }
        }
    }
}

// ================= host =================
extern "C" void kernel_launch(void* const* d_in, const int* in_sizes, int n_in,
                              void* d_out, int out_size, void* d_ws, size_t ws_size,
                              hipStream_t stream) {
    const float* x     = (const float*)d_in[0];
    const int*   ei    = (const int*)d_in[1];
    const float* ea    = (const float*)d_in[2];
    const float* We    = (const float*)d_in[3];
    const float* be    = (const float*)d_in[4];
    const float* W1    = (const float*)d_in[5];
    const float* b1    = (const float*)d_in[6];
    const float* W2    = (const float*)d_in[7];
    const float* b2    = (const float*)d_in[8];
    const float* gamma = (const float*)d_in[9];
    const float* beta  = (const float*)d_in[10];

    const int N = in_sizes[0] / D;
    const int E = in_sizes[1] / 2;
    const int* src = ei;
    const int* dst = ei + E;

    char* ws = (char*)d_ws;
    size_t off = 0;
    auto alloc = [&](size_t bytes) -> size_t {
        size_t o = off;
        off = (off + bytes + 255) & ~(size_t)255;
        return o;
    };
    size_t o_offs   = alloc((size_t)(N + 1) * 4);
    size_t o_counts = alloc((size_t)(N + 1) * 4);
    size_t o_cursor = alloc((size_t)N * 4);
    size_t o_bsum   = alloc(256 * 4);
    size_t o_bofs   = alloc(256 * 4);
    size_t o_perm   = alloc((size_t)E * 4);
    size_t o_srcP   = alloc((size_t)E * 4);
    size_t o_dstP   = alloc((size_t)E * 4);
    size_t o_Wet    = alloc((size_t)D * ED * 2);
    size_t o_W1t    = alloc((size_t)D * D * 2);
    size_t o_W2t    = alloc((size_t)D * D * 2);
    size_t o_xb     = alloc((size_t)N * D * 2);
    size_t o_aggr   = alloc((size_t)N * D * 4);
    size_t need = off;

    if (ws_size >= need) {
        int*   offs   = (int*)(ws + o_offs);
        int*   counts = (int*)(ws + o_counts);
        int*   cursor = (int*)(ws + o_cursor);
        int*   bsum   = (int*)(ws + o_bsum);
        int*   bofs   = (int*)(ws + o_bofs);
        int*   perm   = (int*)(ws + o_perm);
        int*   srcP   = (int*)(ws + o_srcP);
        int*   dstP   = (int*)(ws + o_dstP);
        short* Wet    = (short*)(ws + o_Wet);
        short* W1t    = (short*)(ws + o_W1t);
        short* W2t    = (short*)(ws + o_W2t);
        short* xb     = (short*)(ws + o_xb);
        float* aggr   = (float*)(ws + o_aggr);

        hipMemsetAsync(counts, 0, (size_t)(N + 1) * 4, stream);
        hipMemsetAsync(aggr, 0, (size_t)N * D * 4, stream);
        prep_weights<<<dim3(256), dim3(256), 0, stream>>>(We, W1, W2, Wet, W1t, W2t);
        int n4 = N * D / 4;
        cast_x<<<dim3((n4 + 255) / 256), dim3(256), 0, stream>>>(x, xb, n4);

        hist_kernel<<<dim3((E + 255) / 256), dim3(256), 0, stream>>>(dst, counts, E);
        int nscan = N + 1;
        int nb = (nscan + 255) / 256;
        scan_block<<<dim3(nb), dim3(256), 0, stream>>>(counts, offs, bsum, nscan);
        scan_block<<<dim3(1), dim3(256), 0, stream>>>(bsum, bofs, (int*)nullptr, nb);
        scan_add<<<dim3(nb), dim3(256), 0, stream>>>(offs, bofs, cursor, nscan, N);
        scatter_edges<<<dim3((E + 255) / 256), dim3(256), 0, stream>>>(
            src, dst, cursor, perm, srcP, dstP, E);

        fused_edge<<<dim3((E + 63) / 64), dim3(256), 0, stream>>>(
            ea, perm, srcP, dstP, offs, Wet, be, xb, aggr, E);
        mlp_kernel<<<dim3((N + 63) / 64), dim3(256), 0, stream>>>(
            x, aggr, W1t, b1, W2t, b2, gamma, beta, (float*)d_out, N);
    } else {
        float* aggr = (float*)ws;
        size_t aggrB = (size_t)N * D * sizeof(float);
        short* Wet = (short*)(ws + aggrB);
        short* W1t = Wet + D * ED;
        short* W2t = W1t + D * D;

        hipMemsetAsync(aggr, 0, aggrB, stream);
        prep_weights<<<dim3(256), dim3(256), 0, stream>>>(We, W1, W2, Wet, W1t, W2t);
        edge_kernel_v1<<<dim3((E + 63) / 64), dim3(256), 0, stream>>>(ea, src, dst, Wet, be, x, aggr, E);
        mlp_kernel<<<dim3((N + 63) / 64), dim3(256), 0, stream>>>(
            x, aggr, W1t, b1, W2t, b2, gamma, beta, (float*)d_out, N);
    }
}

// Round 5
// 791.793 us; speedup vs baseline: 1.2203x; 1.0141x over previous
//
#include <hip/hip_runtime.h>
#include <hip/hip_bf16.h>

#define D 256        // IN_DIM == HID
#define ED 64        // EDGE_DIM
#define LN_EPS 1e-5f

typedef __attribute__((ext_vector_type(8))) short short8;
typedef __attribute__((ext_vector_type(4))) short short4v;
typedef __attribute__((ext_vector_type(4))) float f32x4;

__device__ __forceinline__ short bf16b(float f) {
    return __builtin_bit_cast(short, __float2bfloat16(f));
}
__device__ __forceinline__ float bf2f(short s) {
    unsigned u = ((unsigned)(unsigned short)s) << 16;
    return __builtin_bit_cast(float, u);
}

__device__ __forceinline__ short8 pack8(float4 f0, float4 f1) {
    short8 r;
    r[0] = bf16b(f0.x); r[1] = bf16b(f0.y); r[2] = bf16b(f0.z); r[3] = bf16b(f0.w);
    r[4] = bf16b(f1.x); r[5] = bf16b(f1.y); r[6] = bf16b(f1.z); r[7] = bf16b(f1.w);
    return r;
}

// ---------------- prep: transpose weights to bf16 ----------------
__global__ __launch_bounds__(256) void prep_weights(
    const float* __restrict__ We, const float* __restrict__ W1,
    const float* __restrict__ W2,
    short* __restrict__ Wet, short* __restrict__ W1t, short* __restrict__ W2t) {
    int t = blockIdx.x * 256 + threadIdx.x;
    if (t < D * ED) {
        int n = t >> 6, k = t & (ED - 1);
        Wet[t] = bf16b(We[k * D + n]);
    }
    if (t < D * D) {
        int n = t >> 8, k = t & (D - 1);
        W1t[t] = bf16b(W1[k * D + n]);
        W2t[t] = bf16b(W2[k * D + n]);
    }
}

// cast x (f32) -> xb (bf16), vectorized
__global__ __launch_bounds__(256) void cast_x(
    const float* __restrict__ x, short* __restrict__ xb, int n4) {
    int t = blockIdx.x * 256 + threadIdx.x;
    if (t < n4) {
        float4 v = ((const float4*)x)[t];
        short4v s;
        s[0] = bf16b(v.x); s[1] = bf16b(v.y); s[2] = bf16b(v.z); s[3] = bf16b(v.w);
        ((short4v*)xb)[t] = s;
    }
}

// ---------------- CSR build ----------------
__global__ __launch_bounds__(256) void hist_kernel(
    const int* __restrict__ dst, int* __restrict__ counts, int E) {
    int t = blockIdx.x * 256 + threadIdx.x;
    if (t < E) atomicAdd(&counts[dst[t]], 1);
}

__global__ __launch_bounds__(256) void scan_block(
    const int* __restrict__ in, int* __restrict__ out, int* __restrict__ bsum, int n) {
    int t = threadIdx.x;
    int g = blockIdx.x * 256 + t;
    int v = (g < n) ? in[g] : 0;
    int lane = t & 63, w = t >> 6;
    int xs = v;
#pragma unroll
    for (int d2 = 1; d2 < 64; d2 <<= 1) {
        int y = __shfl_up(xs, d2, 64);
        if (lane >= d2) xs += y;
    }
    __shared__ int wsums[4];
    if (lane == 63) wsums[w] = xs;
    __syncthreads();
    int addv = 0;
    for (int i = 0; i < w; i++) addv += wsums[i];
    if (g < n) out[g] = xs - v + addv;          // exclusive
    if (t == 255 && bsum != nullptr) bsum[blockIdx.x] = xs + addv;  // total
}

__global__ __launch_bounds__(256) void scan_add(
    int* __restrict__ offs, const int* __restrict__ bofs,
    int* __restrict__ cursor, int n, int Nn) {
    int g = blockIdx.x * 256 + threadIdx.x;
    if (g < n) {
        int v = offs[g] + bofs[blockIdx.x];
        offs[g] = v;
        if (g < Nn) cursor[g] = v;
    }
}

__global__ __launch_bounds__(256) void scatter_edges(
    const int* __restrict__ src, const int* __restrict__ dst,
    int* __restrict__ cursor, int* __restrict__ perm,
    int* __restrict__ srcP, int* __restrict__ dstP, int E) {
    int t = blockIdx.x * 256 + threadIdx.x;
    if (t < E) {
        int d = dst[t];
        int p = atomicAdd(&cursor[d], 1);
        perm[p] = t;
        srcP[p] = src[t];
        dstP[p] = d;
    }
}

// ---------- fused edge GEMM + segmented aggregation (v3, swapped operands) ----------
// Block = 64 dst-sorted edges, 4 waves; wave w owns edges w*16..w*16+15.
// A-operand = Wet (M = 256 out-cols), B-operand = ea rows (N = 16 edges).
// C/D layout: lane ln = edge, regs/quad = 4 consecutive out-cols -> epilogue
// does in-place LDS RMW: tile[edge][col] = bf16(relu(msg + be + x_src)).
// Then segmented column sums by dst (store if segment contained, else atomic).
__global__ __launch_bounds__(256) void fused_edge(
    const float* __restrict__ ea, const int* __restrict__ perm,
    const int* __restrict__ srcP, const int* __restrict__ dstP,
    const int* __restrict__ offs, const short* __restrict__ Wet,
    const float* __restrict__ be, const short* __restrict__ xb,
    float* __restrict__ aggr, int E) {
    __shared__ short tile[64][D + 8];   // 33.8 KB; stride 264 shorts (132 dwords)
    __shared__ float sbe[D];            // 1 KB
    __shared__ int sdst[64];
    const int t = threadIdx.x;
    const int blockBase = blockIdx.x * 64;

    // ---- Phase A: stage xb[src] rows into tile (coalesced 16B gathers) ----
    {
        const int rt  = t >> 2;     // edge row 0..63
        const int seg = t & 3;      // row quarter (64 cols)
        int p = blockBase + rt;
        int pc = (p < E) ? p : E - 1;
        int sid = srcP[pc];
        if (seg == 0) sdst[rt] = (p < E) ? dstP[pc] : -1;
        sbe[t & (D - 1)] = be[t & (D - 1)];
        const short8* xp = (const short8*)(xb + (long)sid * D + seg * 64);
        short* dp = &tile[rt][seg * 64];
#pragma unroll
        for (int i = 0; i < 8; i++) *(short8*)(dp + i * 8) = xp[i];
    }

    // ---- B fragments: this wave's 16 edge rows (16B gathers, f32->bf16) ----
    const int lane = t & 63;
    const int w    = t >> 6;
    const int q    = lane >> 4;
    const int ln   = lane & 15;
    const int erow = w * 16 + ln;       // tile row / edge slot this lane owns
    long ep = (long)blockBase + erow;
    if (ep >= E) ep = E - 1;
    int eid = perm[ep];
    const float* ear = ea + (long)eid * ED + q * 8;
    float4 f0 = *(const float4*)(ear);
    float4 f1 = *(const float4*)(ear + 4);
    float4 f2 = *(const float4*)(ear + 32);
    float4 f3 = *(const float4*)(ear + 36);
    short8 b0 = pack8(f0, f1);   // B[k=q*8+j][n=ln],  k-step 0
    short8 b1 = pack8(f2, f3);   // k-step 1

    __syncthreads();   // xtile + sbe visible

    // ---- MFMA + in-place epilogue: tile[edge][col] = relu(msg+be+x) ----
#pragma unroll
    for (int mt = 0; mt < 16; mt++) {
        const short* wp = Wet + (mt * 16 + ln) * ED + q * 8;
        short8 a0 = *(const short8*)(wp);        // A[m=mt*16+ln][k=q*8+j]
        short8 a1 = *(const short8*)(wp + 32);
        f32x4 c = {0.f, 0.f, 0.f, 0.f};
        c = __builtin_amdgcn_mfma_f32_16x16x32_bf16(a0, b0, c, 0, 0, 0);
        c = __builtin_amdgcn_mfma_f32_16x16x32_bf16(a1, b1, c, 0, 0, 0);
        // lane holds rows (out-cols) mt*16 + q*4 + r for edge `erow`
        int colBase = mt * 16 + q * 4;
        short4v xm = *(const short4v*)&tile[erow][colBase];   // ds_read_b64
        f32x4 bev = *(const f32x4*)&sbe[colBase];             // ds_read_b128
        short4v o;
#pragma unroll
        for (int r = 0; r < 4; r++) {
            float v = fmaxf(c[r] + bev[r] + bf2f(xm[r]), 0.f);
            o[r] = bf16b(v);
        }
        *(short4v*)&tile[erow][colBase] = o;                  // ds_write_b64
    }
    __syncthreads();

    // ---- Phase D: segmented column-pass; thread t owns column t ----
    const int c = t;
    float s = 0.f;
    int cur = sdst[0];
#pragma unroll
    for (int row = 0; row < 64; row++) {
        int d = sdst[row];
        if (d != cur) {
            if (cur >= 0) {
                int gs = offs[cur], ge = offs[cur + 1];
                float* ap = &aggr[(long)cur * D + c];
                if (gs >= blockBase && ge <= blockBase + 64) *ap = s;
                else unsafeAtomicAdd(ap, s);
            }
            cur = d;
            s = 0.f;
        }
        s += bf2f(tile[row][c]);
    }
    if (cur >= 0) {
        int gs = offs[cur], ge = offs[cur + 1];
        float* ap = &aggr[(long)cur * D + c];
        if (gs >= blockBase && ge <= blockBase + 64) *ap = s;
        else unsafeAtomicAdd(ap, s);
    }
}

// ---------------- fused MLP + LN (z = x + aggr) ----------------
__global__ __launch_bounds__(256) void mlp_kernel(
    const float* __restrict__ x, const float* __restrict__ aggr,
    const short* __restrict__ W1t, const float* __restrict__ b1,
    const short* __restrict__ W2t, const float* __restrict__ b2,
    const float* __restrict__ gamma, const float* __restrict__ beta,
    float* __restrict__ out, int N) {
    __shared__ short tile[64][D + 8];
    const int t = threadIdx.x;
    const int rowBase = blockIdx.x * 64;

    {
        int c4 = t & 63;
        int r0 = t >> 6;
#pragma unroll
        for (int i = 0; i < 16; i++) {
            int row = i * 4 + r0;
            int grow = rowBase + row;
            int gr = grow < N ? grow : N - 1;
            float4 xv = *((const float4*)(x + (long)gr * D) + c4);
            float4 av = *((const float4*)(aggr + (long)gr * D) + c4);
            short4v sv;
            sv[0] = bf16b(xv.x + av.x);
            sv[1] = bf16b(xv.y + av.y);
            sv[2] = bf16b(xv.z + av.z);
            sv[3] = bf16b(xv.w + av.w);
            *(short4v*)&tile[row][c4 * 4] = sv;
        }
    }
    __syncthreads();

    const int lane = t & 63;
    const int w    = t >> 6;
    const int q    = lane >> 4;
    const int ln   = lane & 15;
    const int mrow = w * 16;

    f32x4 acc[16];
#pragma unroll
    for (int nt = 0; nt < 16; nt++) acc[nt] = (f32x4){0.f, 0.f, 0.f, 0.f};
#pragma unroll
    for (int s = 0; s < 8; s++) {
        int k = s * 32 + q * 8;
        short8 a = *(const short8*)&tile[mrow + ln][k];
#pragma unroll
        for (int nt = 0; nt < 16; nt++) {
            short8 b = *(const short8*)(W1t + (nt * 16 + ln) * D + k);
            acc[nt] = __builtin_amdgcn_mfma_f32_16x16x32_bf16(a, b, acc[nt], 0, 0, 0);
        }
    }

#pragma unroll
    for (int nt = 0; nt < 16; nt++) {
        int col = nt * 16 + ln;
        float bv = b1[col];
#pragma unroll
        for (int r = 0; r < 4; r++) {
            float v = fmaxf(acc[nt][r] + bv, 0.f);
            tile[mrow + q * 4 + r][col] = bf16b(v);
        }
    }

    f32x4 acc2[16];
#pragma unroll
    for (int nt = 0; nt < 16; nt++) acc2[nt] = (f32x4){0.f, 0.f, 0.f, 0.f};
#pragma unroll
    for (int s = 0; s < 8; s++) {
        int k = s * 32 + q * 8;
        short8 a = *(const short8*)&tile[mrow + ln][k];
#pragma unroll
        for (int nt = 0; nt < 16; nt++) {
            short8 b = *(const short8*)(W2t + (nt * 16 + ln) * D + k);
            acc2[nt] = __builtin_amdgcn_mfma_f32_16x16x32_bf16(a, b, acc2[nt], 0, 0, 0);
        }
    }

    float sum[4] = {0.f, 0.f, 0.f, 0.f};
    float sumsq[4] = {0.f, 0.f, 0.f, 0.f};
#pragma unroll
    for (int nt = 0; nt < 16; nt++) {
        int col = nt * 16 + ln;
        float b2v = b2[col];
#pragma unroll
        for (int r = 0; r < 4; r++) {
            int row = rowBase + mrow + q * 4 + r;
            int rc = row < N ? row : N - 1;
            float v = fmaxf(acc2[nt][r] + b2v, 0.f) + x[(long)rc * D + col];
            acc2[nt][r] = v;
            sum[r] += v;
            sumsq[r] += v * v;
        }
    }
#pragma unroll
    for (int m = 1; m <= 8; m <<= 1) {
#pragma unroll
        for (int r = 0; r < 4; r++) {
            sum[r]   += __shfl_xor(sum[r], m, 64);
            sumsq[r] += __shfl_xor(sumsq[r], m, 64);
        }
    }
    float mean[4], rstd[4];
#pragma unroll
    for (int r = 0; r < 4; r++) {
        mean[r] = sum[r] * (1.f / 256.f);
        float var = sumsq[r] * (1.f / 256.f) - mean[r] * mean[r];
        rstd[r] = rsqrtf(var + LN_EPS);
    }
#pragma unroll
    for (int nt = 0; nt < 16; nt++) {
        int col = nt * 16 + ln;
        float g = gamma[col], bb = beta[col];
#pragma unroll
        for (int r = 0; r < 4; r++) {
            int row = rowBase + mrow + q * 4 + r;
            if (row < N) {
                out[(long)row * D + col] = (acc2[nt][r] - mean[r]) * rstd[r] * g + bb;
            }
        }
    }
}

// ================= fallback path (round-1, atomics) =================
__global__ __launch_bounds__(256) void edge_kernel_v1(
    const float* __restrict__ ea, const int* __restrict__ src,
    const int* __restrict__ dst, const short* __restrict__ Wet,
    const float* __restrict__ be, const float* __restrict__ x,
    float* __restrict__ aggr, int E) {
    const int lane = threadIdx.x & 63;
    const int w    = threadIdx.x >> 6;
    const int q    = lane >> 4;
    const int ln   = lane & 15;
    const long eBase = (long)blockIdx.x * 64 + w * 16;
    long em = eBase + ln;
    if (em >= E) em = E - 1;
    const float* ear = ea + em * ED + q * 8;
    float4 f0 = *(const float4*)(ear);
    float4 f1 = *(const float4*)(ear + 4);
    float4 f2 = *(const float4*)(ear + 32);
    float4 f3 = *(const float4*)(ear + 36);
    short8 a0 = pack8(f0, f1);
    short8 a1 = pack8(f2, f3);
    f32x4 acc[16];
#pragma unroll
    for (int nt = 0; nt < 16; nt++) {
        const short* wp = Wet + (nt * 16 + ln) * ED + q * 8;
        short8 b0 = *(const short8*)(wp);
        short8 b1 = *(const short8*)(wp + 32);
        f32x4 c = {0.f, 0.f, 0.f, 0.f};
        c = __builtin_amdgcn_mfma_f32_16x16x32_bf16(a0, b0, c, 0, 0, 0);
        c = __builtin_amdgcn_mfma_f32_16x16x32_bf16(a1, b1, c, 0, 0, 0);
        acc[nt] = c;
    }
    int srcs[4], dsts[4];
    bool valid[4];
#pragma unroll
    for (int r = 0; r < 4; r++) {
        long e = eBase + q * 4 + r;
        valid[r] = (e < E);
        long ec = valid[r] ? e : 0;
        srcs[r] = src[ec];
        dsts[r] = dst[ec];
    }
#pragma unroll
    for (int nt = 0; nt < 16; nt++) {
        int col = nt * 16 + ln;
        float bev = be[col];
#pragma unroll
        for (int r = 0; r < 4; r++) {
            if (valid[r]) {
                float v = acc[nt][r] + bev + x[(long)srcs[r] * D + col];
                v = fmaxf(v, 0.f);
                unsafeAtomicAdd(&aggr[(long)dsts[r] * D + col], v);
            }
        }
    }
}

// ================= host =================
extern "C" void kernel_launch(void* const* d_in, const int* in_sizes, int n_in,
                              void* d_out, int out_size, void* d_ws, size_t ws_size,
                              hipStream_t stream) {
    const float* x     = (const float*)d_in[0];
    const int*   ei    = (const int*)d_in[1];
    const float* ea    = (const float*)d_in[2];
    const float* We    = (const float*)d_in[3];
    const float* be    = (const float*)d_in[4];
    const float* W1    = (const float*)d_in[5];
    const float* b1    = (const float*)d_in[6];
    const float* W2    = (const float*)d_in[7];
    const float* b2    = (const float*)d_in[8];
    const float* gamma = (const float*)d_in[9];
    const float* beta  = (const float*)d_in[10];

    const int N = in_sizes[0] / D;
    const int E = in_sizes[1] / 2;
    const int* src = ei;
    const int* dst = ei + E;

    char* ws = (char*)d_ws;
    size_t off = 0;
    auto alloc = [&](size_t bytes) -> size_t {
        size_t o = off;
        off = (off + bytes + 255) & ~(size_t)255;
        return o;
    };
    size_t o_offs   = alloc((size_t)(N + 1) * 4);
    size_t o_counts = alloc((size_t)(N + 1) * 4);
    size_t o_cursor = alloc((size_t)N * 4);
    size_t o_bsum   = alloc(256 * 4);
    size_t o_bofs   = alloc(256 * 4);
    size_t o_perm   = alloc((size_t)E * 4);
    size_t o_srcP   = alloc((size_t)E * 4);
    size_t o_dstP   = alloc((size_t)E * 4);
    size_t o_Wet    = alloc((size_t)D * ED * 2);
    size_t o_W1t    = alloc((size_t)D * D * 2);
    size_t o_W2t    = alloc((size_t)D * D * 2);
    size_t o_xb     = alloc((size_t)N * D * 2);
    size_t o_aggr   = alloc((size_t)N * D * 4);
    size_t need = off;

    if (ws_size >= need) {
        int*   offs   = (int*)(ws + o_offs);
        int*   counts = (int*)(ws + o_counts);
        int*   cursor = (int*)(ws + o_cursor);
        int*   bsum   = (int*)(ws + o_bsum);
        int*   bofs   = (int*)(ws + o_bofs);
        int*   perm   = (int*)(ws + o_perm);
        int*   srcP   = (int*)(ws + o_srcP);
        int*   dstP   = (int*)(ws + o_dstP);
        short* Wet    = (short*)(ws + o_Wet);
        short* W1t    = (short*)(ws + o_W1t);
        short* W2t    = (short*)(ws + o_W2t);
        short* xb     = (short*)(ws + o_xb);
        float* aggr   = (float*)(ws + o_aggr);

        hipMemsetAsync(counts, 0, (size_t)(N + 1) * 4, stream);
        hipMemsetAsync(aggr, 0, (size_t)N * D * 4, stream);
        prep_weights<<<dim3(256), dim3(256), 0, stream>>>(We, W1, W2, Wet, W1t, W2t);
        int n4 = N * D / 4;
        cast_x<<<dim3((n4 + 255) / 256), dim3(256), 0, stream>>>(x, xb, n4);

        hist_kernel<<<dim3((E + 255) / 256), dim3(256), 0, stream>>>(dst, counts, E);
        int nscan = N + 1;
        int nb = (nscan + 255) / 256;
        scan_block<<<dim3(nb), dim3(256), 0, stream>>>(counts, offs, bsum, nscan);
        scan_block<<<dim3(1), dim3(256), 0, stream>>>(bsum, bofs, (int*)nullptr, nb);
        scan_add<<<dim3(nb), dim3(256), 0, stream>>>(offs, bofs, cursor, nscan, N);
        scatter_edges<<<dim3((E + 255) / 256), dim3(256), 0, stream>>>(
            src, dst, cursor, perm, srcP, dstP, E);

        fused_edge<<<dim3((E + 63) / 64), dim3(256), 0, stream>>>(
            ea, perm, srcP, dstP, offs, Wet, be, xb, aggr, E);
        mlp_kernel<<<dim3((N + 63) / 64), dim3(256), 0, stream>>>(
            x, aggr, W1t, b1, W2t, b2, gamma, beta, (float*)d_out, N);
    } else {
        float* aggr = (float*)ws;
        size_t aggrB = (size_t)N * D * sizeof(float);
        short* Wet = (short*)(ws + aggrB);
        short* W1t = Wet + D * ED;
        short* W2t = W1t + D * D;

        hipMemsetAsync(aggr, 0, aggrB, stream);
        prep_weights<<<dim3(256), dim3(256), 0, stream>>>(We, W1, W2, Wet, W1t, W2t);
        edge_kernel_v1<<<dim3((E + 63) / 64), dim3(256), 0, stream>>>(ea, src, dst, Wet, be, x, aggr, E);
        mlp_kernel<<<dim3((N + 63) / 64), dim3(256), 0, stream>>>(
            x, aggr, W1t, b1, W2t, b2, gamma, beta, (float*)d_out, N);
    }
}